// Round 14
// baseline (497.897 us; speedup 1.0000x reference)
//
#include <hip/hip_runtime.h>
#include <math.h>

// Problem constants: N=20000, E=320000, C=64, NS=4, NB=8, NH=64
#define PI_F        3.14159265358979323846f
#define SQRT2_F     1.41421356237309515f
#define SQRT3_F     1.73205080756887729f
#define INV_SQRT3_F 0.57735026918962576f
#define INV_AVG     0.25f   // 1/sqrt(16)

#define N_NODES 20000
#define N_EDGES 320000

typedef float v2f __attribute__((ext_vector_type(2)));
typedef float v4f __attribute__((ext_vector_type(4)));

__device__ __forceinline__ float swish_f(float x) {
    return x / (1.f + __expf(-x));
}

// ---------------------------------------------------------------------------
// SESSION LAWS (measured r0-r13):
//  * REGISTER LAW: arch-VGPR alloc = 256/min_waves. k_edge fits only w=4
//    (r1/r3/r10 all spilled; WRITE_SIZE tripwire). (256,4) PERMANENT.
//  * k_edge plateau: ~252us @ VALUBusy 58, Occ 40, HBM 19% — latency-bound,
//    no saturated pipe. Resisted occupancy (x3), VMEM-cut (r8), VALU-cut
//    (r9), shuffle-cut (r11). Remaining lever: bf16-MFMA phase B (absmax
//    risk at observed 0.125). PARKED.
//  * AMORTIZATION: no s_load activation chains (r4); LDS staging + uniform
//    ds_read broadcast works (r6).
//  * kernel_launch: ONLY kernel launches (r7). No d_ws cross-iteration
//    caching (r12: re-poison + checksum atomic contention).
//  * k_edge band on identical bytes: 252-291us (container variance).
//  * r14: node_down act staged in TWO 16KB halves (i-order preserved ->
//    bit-identical). LDS 48->32KB, 3->5 blocks/CU. Tests whether node_down
//    is latency-bound (win) or L2-BW-bound (null).
// ---------------------------------------------------------------------------
__global__ __launch_bounds__(256, 8) void k_zero_cnt(int* __restrict__ cnt) {
    const int i = blockIdx.x * 256 + threadIdx.x;
    if (i < N_NODES) cnt[i] = 0;
}
__global__ __launch_bounds__(256, 8) void k_hist(const int* __restrict__ rcv,
                                                 int* __restrict__ cnt) {
    const int e = blockIdx.x * 256 + threadIdx.x;
    if (e < N_EDGES) atomicAdd(&cnt[rcv[e]], 1);
}
__global__ __launch_bounds__(1024) void k_scan(const int* __restrict__ cnt,
                                               int* __restrict__ cursor) {
    __shared__ int part[1024];
    const int t = threadIdx.x;
    const int base = t * 20;
    int s = 0;
    #pragma unroll
    for (int j = 0; j < 20; ++j) {
        const int idx = base + j;
        if (idx < N_NODES) s += cnt[idx];
    }
    part[t] = s;
    __syncthreads();
    for (int d = 1; d < 1024; d <<= 1) {
        const int v = (t >= d) ? part[t - d] : 0;
        __syncthreads();
        part[t] += v;
        __syncthreads();
    }
    int run = (t == 0) ? 0 : part[t - 1];
    for (int j = 0; j < 20; ++j) {
        const int idx = base + j;
        if (idx < N_NODES) { cursor[idx] = run; run += cnt[idx]; }
    }
}
__global__ __launch_bounds__(256, 8) void k_scatter(const int* __restrict__ rcv,
                                                    int* __restrict__ cursor,
                                                    int* __restrict__ perm) {
    const int e = blockIdx.x * 256 + threadIdx.x;
    if (e < N_EDGES) {
        const int pos = atomicAdd(&cursor[rcv[e]], 1);
        perm[pos] = e;
    }
}

// ---------------------------------------------------------------------------
// K1 v4: LDS-broadcast amortized + quad-transposed epilogue (r8-r13 measured).
// ---------------------------------------------------------------------------
__global__ __launch_bounds__(256) void k_node_up(
    const float* __restrict__ ns, const float* __restrict__ nv,
    const float* __restrict__ Wus, const float* __restrict__ Wuv,
    float* __restrict__ s_up, float* __restrict__ v_up,
    float* __restrict__ agg_s, float* __restrict__ agg_v)
{
    __shared__ v4f actu[16*64];   // 16KB: [n][i] = {s_i, v_i0, v_i1, v_i2}

    const int tid  = threadIdx.x;
    const int lane = tid & 63;
    const int wq   = __builtin_amdgcn_readfirstlane(tid >> 6);
    const int nb   = blockIdx.x * 16;

    #pragma unroll
    for (int k = 0; k < 4; ++k) {
        const int idx = k*256 + tid;
        const int n = idx >> 6, i = idx & 63;
        const float* nvp = nv + (nb + n)*192 + 3*i;
        actu[idx] = (v4f){ns[(nb + n)*64 + i], nvp[0], nvp[1], nvp[2]};
    }
    __syncthreads();

    float acc[4] = {0.f, 0.f, 0.f, 0.f};
    float a0[4] = {}, a1[4] = {}, a2[4] = {};
    const v4f* aw = actu + wq*4*64;
    for (int i = 0; i < 64; ++i) {
        const float wu = Wus[i*64 + lane];
        const float wv = Wuv[i*64 + lane];
        #pragma unroll
        for (int j = 0; j < 4; ++j) {
            const v4f a = aw[j*64 + i];      // uniform ds_read_b128 broadcast
            acc[j] = fmaf(a.x, wu, acc[j]);
            a0[j]  = fmaf(a.y, wv, a0[j]);
            a1[j]  = fmaf(a.z, wv, a1[j]);
            a2[j]  = fmaf(a.w, wv, a2[j]);
        }
    }
    const int cc = lane & 15, nt = lane >> 4;   // channel = nt*16 + cc
    #pragma unroll
    for (int j = 0; j < 4; ++j) {
        const int n = nb + wq*4 + j;
        s_up[n*64 + cc*4 + nt] = acc[j];             // quad-transposed
        float* vq = v_up + n*192 + cc*12 + nt*3;     // quad-transposed
        vq[0] = a0[j]; vq[1] = a1[j]; vq[2] = a2[j];
        agg_s[n*128 + lane]      = 0.f;
        agg_s[n*128 + 64 + lane] = 0.f;
        #pragma unroll
        for (int k = 0; k < 6; ++k) agg_v[n*384 + k*64 + lane] = 0.f;
    }
}

// ---------------------------------------------------------------------------
// K2 v13 (META-LDS AT w=4, r11/r13 measured-best — byte-identical).
// ---------------------------------------------------------------------------
__global__ __launch_bounds__(256, 4) void k_edge(
    const float* __restrict__ vecs,
    const int*   __restrict__ snd_idx, const int* __restrict__ rcv_idx,
    const int*   __restrict__ perm,
    const float* __restrict__ W0, const float* __restrict__ W1,
    const float* __restrict__ W2,
    const float* __restrict__ s_up, const float* __restrict__ v_up,
    float* __restrict__ agg_s, float* __restrict__ agg_v)
{
    __shared__ float hv[64*68];   // [ch][le], stride 68; holds h1 then h2
    __shared__ v4f   meta[64*2];  // [edge]: {rcvf,sndf,Y0,Y1},{Y2,s1,c1,pref}

    const int tid  = threadIdx.x;
    const int lane = tid & 63;
    const int wq   = __builtin_amdgcn_readfirstlane(tid >> 6);
    const int e0   = blockIdx.x * 64;
    const int c    = lane & 15, q = lane >> 4;
    const float* mb = (const float*)meta;

    // --- edge metadata -> LDS (each wave writes identical values: benign) ---
    {
        const int pe  = perm[e0 + lane];
        const int rcv = rcv_idx[pe];
        const int snd = snd_idx[pe];
        const float vx = vecs[pe*3+0], vy = vecs[pe*3+1], vz = vecs[pe*3+2];
        const float x  = sqrtf(vx*vx + vy*vy + vz*vz);
        const float sx = (x == 0.f) ? 1.f : x;
        const float ys = SQRT3_F / sx;
        float s1, c1;
        __sincosf(PI_F * x, &s1, &c1);
        const float u  = fminf(x, 1.f);
        const float u2 = u*u, u3 = u2*u;
        const float u6 = u3*u3, u7 = u6*u, u8 = u6*u2;
        const float env = (x < 1.f) ? (1.f - 28.f*u6 + 48.f*u7 - 21.f*u8) : 0.f;
        // mask folded: x==0 -> pref=0 -> h1=0 -> h2=swish(0)=0 -> mix==0
        const float pref = (x == 0.f) ? 0.f : (SQRT2_F * env / sx);
        meta[lane*2 + 0] = (v4f){__int_as_float(rcv), __int_as_float(snd),
                                 vx*ys, vy*ys};
        meta[lane*2 + 1] = (v4f){vz*ys, s1, c1, pref};
    }

    // ---- A1: bessel + layer0 -> h1; scalars from own-wave meta entries ----
    float h1o[16];
    #pragma unroll 4
    for (int t = 0; t < 16; ++t) {
        const int le = wq*16 + t;
        const v4f m1 = meta[le*2 + 1];       // uniform addr -> broadcast
        const float pref = m1.w;
        const float twoc = 2.f * m1.z;
        float acc1 = 0.f;
        float sn = m1.y, snm1 = 0.f;
        #pragma unroll
        for (int b = 0; b < 8; ++b) {
            acc1 = fmaf(sn, W0[b*64 + lane], acc1);
            const float snext = fmaf(twoc, sn, -snm1);
            snm1 = sn; sn = snext;
        }
        h1o[t] = swish_f(pref * acc1);
    }
    {   // write own channel-row, own wave's 16 edge-columns: 4x ds_write_b128
        float* dst = hv + lane*68 + wq*16;
        #pragma unroll
        for (int k = 0; k < 4; ++k)
            ((v4f*)dst)[k] = (v4f){h1o[4*k], h1o[4*k+1], h1o[4*k+2], h1o[4*k+3]};
    }
    // no barrier: A2 reads only columns wq*16..+15, written by this wave.

    // ---- A2: h2 = swish(h1 @ W1); own rows/cols, in-place ----
    {
        v2f acc2[8];
        #pragma unroll
        for (int tp = 0; tp < 8; ++tp) acc2[tp] = (v2f){0.f, 0.f};
        const float* hbase = hv + wq*16;
        for (int i = 0; i < 64; ++i) {
            const float w = W1[i*64 + lane];           // coalesced, L1-hot
            const v2f wv = {w, w};
            const v4f* hp4 = (const v4f*)(hbase + i*68);
            #pragma unroll
            for (int k = 0; k < 4; ++k) {
                const v4f h4 = hp4[k];
                const v2f hlo = __builtin_shufflevector(h4, h4, 0, 1);
                const v2f hhi = __builtin_shufflevector(h4, h4, 2, 3);
                acc2[2*k]   = __builtin_elementwise_fma(hlo, wv, acc2[2*k]);
                acc2[2*k+1] = __builtin_elementwise_fma(hhi, wv, acc2[2*k+1]);
            }
        }
        float* dst = hv + lane*68 + wq*16;
        #pragma unroll
        for (int k = 0; k < 4; ++k)
            ((v4f*)dst)[k] = (v4f){swish_f(acc2[2*k][0]),   swish_f(acc2[2*k][1]),
                                   swish_f(acc2[2*k+1][0]), swish_f(acc2[2*k+1][1])};
    }
    __syncthreads();

    // ---- B: mixp[t/2][ntl] pairs; lane (c,q) of wave wq accumulates
    //      mix[64wq + ntl*16 + c][le = q*16 + t] for t=0..15.
    v2f mixp[8][4];
    #pragma unroll
    for (int tp = 0; tp < 8; ++tp)
        #pragma unroll
        for (int j = 0; j < 4; ++j) mixp[tp][j] = (v2f){0.f, 0.f};
    {
        const float* W2c = W2 + 64*wq + c;
        const float* hq  = hv + q*16;
        for (int i = 0; i < 64; ++i) {
            const float w0 = W2c[i*256 +  0];
            const float w1 = W2c[i*256 + 16];
            const float w2 = W2c[i*256 + 32];
            const float w3 = W2c[i*256 + 48];
            const v2f w0v = {w0,w0}, w1v = {w1,w1}, w2v = {w2,w2}, w3v = {w3,w3};
            const v4f* hp4 = (const v4f*)(hq + i*68);
            #pragma unroll
            for (int k = 0; k < 4; ++k) {
                const v4f h4 = hp4[k];
                const v2f hlo = __builtin_shufflevector(h4, h4, 0, 1);
                const v2f hhi = __builtin_shufflevector(h4, h4, 2, 3);
                mixp[2*k][0]   = __builtin_elementwise_fma(hlo, w0v, mixp[2*k][0]);
                mixp[2*k][1]   = __builtin_elementwise_fma(hlo, w1v, mixp[2*k][1]);
                mixp[2*k][2]   = __builtin_elementwise_fma(hlo, w2v, mixp[2*k][2]);
                mixp[2*k][3]   = __builtin_elementwise_fma(hlo, w3v, mixp[2*k][3]);
                mixp[2*k+1][0] = __builtin_elementwise_fma(hhi, w0v, mixp[2*k+1][0]);
                mixp[2*k+1][1] = __builtin_elementwise_fma(hhi, w1v, mixp[2*k+1][1]);
                mixp[2*k+1][2] = __builtin_elementwise_fma(hhi, w2v, mixp[2*k+1][2]);
                mixp[2*k+1][3] = __builtin_elementwise_fma(hhi, w3v, mixp[2*k+1][3]);
            }
        }
    }
    #define MIXR(t,j) (mixp[(t)>>1][j][(t)&1])

    // ---- C: per-q-group segmented scatter-add; meta from LDS broadcast ----
    int cur = -1;
    if (wq == 0) {            // agg_s[:, ntl*16+c] += msv * mix0
        float ra0=0.f, ra1=0.f, ra2=0.f, ra3=0.f;
        #pragma unroll
        for (int t = 0; t < 16; ++t) {
            const int el = (lane & 48) + t;
            const v2f rs = *(const v2f*)(mb + el*8);   // {rcvf, sndf}
            const int rcv = __float_as_int(rs.x);
            const int snd = __float_as_int(rs.y);
            if (rcv != cur) {
                if (cur >= 0) {
                    float* p = agg_s + cur*128 + c;
                    unsafeAtomicAdd(p,      ra0);
                    unsafeAtomicAdd(p + 16, ra1);
                    unsafeAtomicAdd(p + 32, ra2);
                    unsafeAtomicAdd(p + 48, ra3);
                }
                ra0 = ra1 = ra2 = ra3 = 0.f; cur = rcv;
            }
            const v4f sv = *(const v4f*)(s_up + snd*64 + c*4);
            ra0 = fmaf(sv.x, MIXR(t,0), ra0);
            ra1 = fmaf(sv.y, MIXR(t,1), ra1);
            ra2 = fmaf(sv.z, MIXR(t,2), ra2);
            ra3 = fmaf(sv.w, MIXR(t,3), ra3);
        }
        float* p = agg_s + cur*128 + c;
        unsafeAtomicAdd(p,      ra0);
        unsafeAtomicAdd(p + 16, ra1);
        unsafeAtomicAdd(p + 32, ra2);
        unsafeAtomicAdd(p + 48, ra3);
    } else if (wq == 1) {     // agg_s[:, 64+ntl*16+c] += (mv.Y)/sqrt3 * mix1
        float ra0=0.f, ra1=0.f, ra2=0.f, ra3=0.f;
        #pragma unroll
        for (int t = 0; t < 16; ++t) {
            const int el = (lane & 48) + t;
            const v4f m0 = meta[el*2];                 // {rcvf,sndf,Y0,Y1}
            const float Y2 = mb[el*8 + 4];
            const int rcv = __float_as_int(m0.x);
            const int snd = __float_as_int(m0.y);
            const float Y0 = m0.z, Y1 = m0.w;
            if (rcv != cur) {
                if (cur >= 0) {
                    float* p = agg_s + cur*128 + 64 + c;
                    unsafeAtomicAdd(p,      ra0);
                    unsafeAtomicAdd(p + 16, ra1);
                    unsafeAtomicAdd(p + 32, ra2);
                    unsafeAtomicAdd(p + 48, ra3);
                }
                ra0 = ra1 = ra2 = ra3 = 0.f; cur = rcv;
            }
            const float* vb = v_up + snd*192 + c*12;
            const v4f f0 = *(const v4f*)(vb);
            const v4f f1 = *(const v4f*)(vb + 4);
            const v4f f2 = *(const v4f*)(vb + 8);
            const float t00 = (f0.x*Y0 + f0.y*Y1 + f0.z*Y2) * INV_SQRT3_F;
            const float t01 = (f0.w*Y0 + f1.x*Y1 + f1.y*Y2) * INV_SQRT3_F;
            const float t02 = (f1.z*Y0 + f1.w*Y1 + f2.x*Y2) * INV_SQRT3_F;
            const float t03 = (f2.y*Y0 + f2.z*Y1 + f2.w*Y2) * INV_SQRT3_F;
            ra0 = fmaf(t00, MIXR(t,0), ra0);
            ra1 = fmaf(t01, MIXR(t,1), ra1);
            ra2 = fmaf(t02, MIXR(t,2), ra2);
            ra3 = fmaf(t03, MIXR(t,3), ra3);
        }
        float* p = agg_s + cur*128 + 64 + c;
        unsafeAtomicAdd(p,      ra0);
        unsafeAtomicAdd(p + 16, ra1);
        unsafeAtomicAdd(p + 32, ra2);
        unsafeAtomicAdd(p + 48, ra3);
    } else if (wq == 2) {     // agg_v[:, ntl*16+c, m] += mv_m * mix2
        float rv[4][3];
        #pragma unroll
        for (int i = 0; i < 4; ++i) { rv[i][0]=0.f; rv[i][1]=0.f; rv[i][2]=0.f; }
        #pragma unroll
        for (int t = 0; t < 16; ++t) {
            const int el = (lane & 48) + t;
            const v2f rs = *(const v2f*)(mb + el*8);   // {rcvf, sndf}
            const int rcv = __float_as_int(rs.x);
            const int snd = __float_as_int(rs.y);
            if (rcv != cur) {
                if (cur >= 0) {
                    float* p = agg_v + cur*384 + c*3;
                    #pragma unroll
                    for (int ntl = 0; ntl < 4; ++ntl)
                        #pragma unroll
                        for (int m = 0; m < 3; ++m)
                            unsafeAtomicAdd(p + ntl*48 + m, rv[ntl][m]);
                }
                #pragma unroll
                for (int i = 0; i < 4; ++i) { rv[i][0]=0.f; rv[i][1]=0.f; rv[i][2]=0.f; }
                cur = rcv;
            }
            const float* vb = v_up + snd*192 + c*12;
            const v4f f0 = *(const v4f*)(vb);
            const v4f f1 = *(const v4f*)(vb + 4);
            const v4f f2 = *(const v4f*)(vb + 8);
            const float mx0 = MIXR(t,0);
            const float mx1 = MIXR(t,1);
            const float mx2 = MIXR(t,2);
            const float mx3 = MIXR(t,3);
            rv[0][0] = fmaf(f0.x, mx0, rv[0][0]);
            rv[0][1] = fmaf(f0.y, mx0, rv[0][1]);
            rv[0][2] = fmaf(f0.z, mx0, rv[0][2]);
            rv[1][0] = fmaf(f0.w, mx1, rv[1][0]);
            rv[1][1] = fmaf(f1.x, mx1, rv[1][1]);
            rv[1][2] = fmaf(f1.y, mx1, rv[1][2]);
            rv[2][0] = fmaf(f1.z, mx2, rv[2][0]);
            rv[2][1] = fmaf(f1.w, mx2, rv[2][1]);
            rv[2][2] = fmaf(f2.x, mx2, rv[2][2]);
            rv[3][0] = fmaf(f2.y, mx3, rv[3][0]);
            rv[3][1] = fmaf(f2.z, mx3, rv[3][1]);
            rv[3][2] = fmaf(f2.w, mx3, rv[3][2]);
        }
        float* p = agg_v + cur*384 + c*3;
        #pragma unroll
        for (int ntl = 0; ntl < 4; ++ntl)
            #pragma unroll
            for (int m = 0; m < 3; ++m)
                unsafeAtomicAdd(p + ntl*48 + m, rv[ntl][m]);
    } else {                  // agg_v[:, 64+ntl*16+c, m] += msv * Y_m * mix3
        float rv[4][3];
        #pragma unroll
        for (int i = 0; i < 4; ++i) { rv[i][0]=0.f; rv[i][1]=0.f; rv[i][2]=0.f; }
        #pragma unroll
        for (int t = 0; t < 16; ++t) {
            const int el = (lane & 48) + t;
            const v4f m0 = meta[el*2];                 // {rcvf,sndf,Y0,Y1}
            const float Y2 = mb[el*8 + 4];
            const int rcv = __float_as_int(m0.x);
            const int snd = __float_as_int(m0.y);
            const float Y0 = m0.z, Y1 = m0.w;
            if (rcv != cur) {
                if (cur >= 0) {
                    float* p = agg_v + cur*384 + 192 + c*3;
                    #pragma unroll
                    for (int ntl = 0; ntl < 4; ++ntl)
                        #pragma unroll
                        for (int m = 0; m < 3; ++m)
                            unsafeAtomicAdd(p + ntl*48 + m, rv[ntl][m]);
                }
                #pragma unroll
                for (int i = 0; i < 4; ++i) { rv[i][0]=0.f; rv[i][1]=0.f; rv[i][2]=0.f; }
                cur = rcv;
            }
            const v4f sv = *(const v4f*)(s_up + snd*64 + c*4);
            const float mm0 = sv.x * MIXR(t,0);
            const float mm1 = sv.y * MIXR(t,1);
            const float mm2 = sv.z * MIXR(t,2);
            const float mm3 = sv.w * MIXR(t,3);
            rv[0][0] = fmaf(mm0, Y0, rv[0][0]);
            rv[0][1] = fmaf(mm0, Y1, rv[0][1]);
            rv[0][2] = fmaf(mm0, Y2, rv[0][2]);
            rv[1][0] = fmaf(mm1, Y0, rv[1][0]);
            rv[1][1] = fmaf(mm1, Y1, rv[1][1]);
            rv[1][2] = fmaf(mm1, Y2, rv[1][2]);
            rv[2][0] = fmaf(mm2, Y0, rv[2][0]);
            rv[2][1] = fmaf(mm2, Y1, rv[2][1]);
            rv[2][2] = fmaf(mm2, Y2, rv[2][2]);
            rv[3][0] = fmaf(mm3, Y0, rv[3][0]);
            rv[3][1] = fmaf(mm3, Y1, rv[3][1]);
            rv[3][2] = fmaf(mm3, Y2, rv[3][2]);
        }
        float* p = agg_v + cur*384 + 192 + c*3;
        #pragma unroll
        for (int ntl = 0; ntl < 4; ++ntl)
            #pragma unroll
            for (int m = 0; m < 3; ++m)
                unsafeAtomicAdd(p + ntl*48 + m, rv[ntl][m]);
    }
    #undef MIXR
}

// ---------------------------------------------------------------------------
// K3 v5 (HALF-STAGED act): r6 structure, but act staged in two 16KB halves
// (i=0..63 compute, re-stage, i=64..127 compute). i-order preserved ->
// bit-identical accumulation. LDS 48KB -> 32KB => 3 -> 5 blocks/CU.
// ---------------------------------------------------------------------------
__global__ __launch_bounds__(256) void k_node_down(
    const float* __restrict__ ns, const float* __restrict__ nv,
    const int*   __restrict__ spec_idx,
    const float* __restrict__ Wds, const float* __restrict__ Wdv,
    const float* __restrict__ Wsks, const float* __restrict__ Wskv,
    const float* __restrict__ agg_s, const float* __restrict__ agg_v,
    float* __restrict__ out)
{
    __shared__ v4f act[16*64];   // 16KB: half of the agg rows at a time
    __shared__ v4f skp[16*64];   // 16KB: [n][i] = {s, v0, v1, v2}

    const int tid  = threadIdx.x;
    const int lane = tid & 63;
    const int wq   = __builtin_amdgcn_readfirstlane(tid >> 6);
    const int nb   = blockIdx.x * 16;

    // stage skp (1024 entries, 4/thread) + act half 0 (i=0..63)
    #pragma unroll
    for (int k = 0; k < 4; ++k) {
        const int idx = k*256 + tid;
        const int n = idx >> 6, i = idx & 63;
        const float* nvp = nv + (nb + n)*192 + 3*i;
        skp[idx] = (v4f){ns[(nb + n)*64 + i], nvp[0], nvp[1], nvp[2]};
        const float a = agg_s[(nb + n)*128 + i] * INV_AVG;
        const float* av = agg_v + (nb + n)*384 + 3*i;
        act[idx] = (v4f){a, av[0]*INV_AVG, av[1]*INV_AVG, av[2]*INV_AVG};
    }
    __syncthreads();

    float s0[4] = {}, s1[4] = {}, v0[4] = {}, v1[4] = {}, v2[4] = {};

    // down-projection, first half (i = 0..63)
    const v4f* aw = act + wq*4*64;
    for (int i = 0; i < 64; ++i) {
        const float wd0 = Wds[i*128 + lane];
        const float wd1 = Wds[i*128 + 64 + lane];
        const float wdv = Wdv[i*64 + lane];
        #pragma unroll
        for (int j = 0; j < 4; ++j) {
            const v4f a = aw[j*64 + i];      // uniform ds_read_b128 broadcast
            s0[j] = fmaf(a.x, wd0, s0[j]);
            s1[j] = fmaf(a.x, wd1, s1[j]);
            v0[j] = fmaf(a.y, wdv, v0[j]);
            v1[j] = fmaf(a.z, wdv, v1[j]);
            v2[j] = fmaf(a.w, wdv, v2[j]);
        }
    }
    __syncthreads();   // everyone done reading half 0

    // stage act half 1 (i = 64..127)
    #pragma unroll
    for (int k = 0; k < 4; ++k) {
        const int idx = k*256 + tid;
        const int n = idx >> 6, i = idx & 63;
        const float a = agg_s[(nb + n)*128 + 64 + i] * INV_AVG;
        const float* av = agg_v + (nb + n)*384 + 3*(64 + i);
        act[idx] = (v4f){a, av[0]*INV_AVG, av[1]*INV_AVG, av[2]*INV_AVG};
    }
    __syncthreads();

    // down-projection, second half (i = 64..127)
    for (int i = 64; i < 128; ++i) {
        const float wd0 = Wds[i*128 + lane];
        const float wd1 = Wds[i*128 + 64 + lane];
        const float wdv = Wdv[i*64 + lane];
        #pragma unroll
        for (int j = 0; j < 4; ++j) {
            const v4f a = aw[j*64 + (i - 64)];
            s0[j] = fmaf(a.x, wd0, s0[j]);
            s1[j] = fmaf(a.x, wd1, s1[j]);
            v0[j] = fmaf(a.y, wdv, v0[j]);
            v1[j] = fmaf(a.z, wdv, v1[j]);
            v2[j] = fmaf(a.w, wdv, v2[j]);
        }
    }

    // specie skip: per-node weight streams, LDS activations (skp intact)
    const int n0 = nb + wq*4;
    const float* Ws_j[4]; const float* Wv_j[4];
    #pragma unroll
    for (int j = 0; j < 4; ++j) {
        const int spec = __builtin_amdgcn_readfirstlane(spec_idx[n0 + j]);
        Ws_j[j] = Wsks + spec*8192;   // (64,128)
        Wv_j[j] = Wskv + spec*4096;   // (64,64)
    }
    const v4f* sw = skp + wq*4*64;
    for (int i = 0; i < 64; ++i) {
        #pragma unroll
        for (int j = 0; j < 4; ++j) {
            const v4f a = sw[j*64 + i];      // uniform ds_read_b128 broadcast
            s0[j] = fmaf(a.x, Ws_j[j][i*128 + lane], s0[j]);
            s1[j] = fmaf(a.x, Ws_j[j][i*128 + 64 + lane], s1[j]);
            const float wv = Wv_j[j][i*64 + lane];
            v0[j] = fmaf(a.y, wv, v0[j]);
            v1[j] = fmaf(a.z, wv, v1[j]);
            v2[j] = fmaf(a.w, wv, v2[j]);
        }
    }

    #pragma unroll
    for (int j = 0; j < 4; ++j) {
        const int n = n0 + j;
        const float scal = swish_f(s0[j]);
        const float gate = swish_f(s1[j]);
        out[n*256 + lane]            = scal;
        out[n*256 + 64 + lane*3 + 0] = v0[j] * gate;
        out[n*256 + 64 + lane*3 + 1] = v1[j] * gate;
        out[n*256 + 64 + lane*3 + 2] = v2[j] * gate;
    }
}

// ---------------------------------------------------------------------------
extern "C" void kernel_launch(void* const* d_in, const int* in_sizes, int n_in,
                              void* d_out, int out_size, void* d_ws, size_t ws_size,
                              hipStream_t stream)
{
    (void)in_sizes; (void)n_in; (void)out_size; (void)ws_size;

    const float* vectors      = (const float*)d_in[0];
    const float* node_scalars = (const float*)d_in[1];
    const float* node_vectors = (const float*)d_in[2];
    const int*   node_specie  = (const int*)d_in[3];
    const int*   senders      = (const int*)d_in[4];
    const int*   receivers    = (const int*)d_in[5];
    const float* W_skip_s     = (const float*)d_in[6];
    const float* W_skip_v     = (const float*)d_in[7];
    const float* W_up_s       = (const float*)d_in[8];
    const float* W_up_v       = (const float*)d_in[9];
    const float* W_mlp0       = (const float*)d_in[10];
    const float* W_mlp1       = (const float*)d_in[11];
    const float* W_mlp2       = (const float*)d_in[12];
    const float* W_down_s     = (const float*)d_in[13];
    const float* W_down_v     = (const float*)d_in[14];
    float* out = (float*)d_out;

    // workspace layout: 15,360,000 f32 + perm 320k ints.
    float* ws    = (float*)d_ws;
    float* s_up  = ws;                        // N*64   = 1,280,000 f32 (quad-T)
    float* v_up  = s_up + 1280000;            // N*192  = 3,840,000    (quad-T)
    float* agg_s = v_up + 3840000;            // N*128  = 2,560,000
    float* agg_v = agg_s + 2560000;           // N*384  = 7,680,000
    int*   perm  = (int*)(agg_v + 7680000);   // E ints = 320,000
    int*   cnt    = (int*)agg_s;              // aliased scratch (dead before node_up)
    int*   cursor = cnt + 20000;

    // edge counting sort by receiver (kernels only; no runtime memops)
    hipLaunchKernelGGL(k_zero_cnt, dim3(79),   dim3(256),  0, stream, cnt);
    hipLaunchKernelGGL(k_hist,     dim3(1250), dim3(256),  0, stream, receivers, cnt);
    hipLaunchKernelGGL(k_scan,     dim3(1),    dim3(1024), 0, stream, cnt, cursor);
    hipLaunchKernelGGL(k_scatter,  dim3(1250), dim3(256),  0, stream, receivers, cursor, perm);

    hipLaunchKernelGGL(k_node_up, dim3(1250), dim3(256), 0, stream,
        node_scalars, node_vectors, W_up_s, W_up_v, s_up, v_up, agg_s, agg_v);
    hipLaunchKernelGGL(k_edge, dim3(5000), dim3(256), 0, stream,
        vectors, senders, receivers, perm, W_mlp0, W_mlp1, W_mlp2,
        s_up, v_up, agg_s, agg_v);
    hipLaunchKernelGGL(k_node_down, dim3(1250), dim3(256), 0, stream,
        node_scalars, node_vectors, node_specie, W_down_s, W_down_v,
        W_skip_s, W_skip_v, agg_s, agg_v, out);
}

// Round 15
// 473.482 us; speedup vs baseline: 1.0516x; 1.0516x over previous
//
#include <hip/hip_runtime.h>
#include <math.h>

// Problem constants: N=20000, E=320000, C=64, NS=4, NB=8, NH=64
#define PI_F        3.14159265358979323846f
#define SQRT2_F     1.41421356237309515f
#define SQRT3_F     1.73205080756887729f
#define INV_SQRT3_F 0.57735026918962576f
#define INV_AVG     0.25f   // 1/sqrt(16)

#define N_NODES 20000
#define N_EDGES 320000

typedef float v2f __attribute__((ext_vector_type(2)));
typedef float v4f __attribute__((ext_vector_type(4)));

__device__ __forceinline__ float swish_f(float x) {
    return x / (1.f + __expf(-x));
}

// ---------------------------------------------------------------------------
// FINAL CONFIGURATION (= r13 bytes, measured session best 476.9us; r11
// measured 478.2us on the same bytes). Session characterization:
//  * k_edge ~252us: latency-bound at structural 40% occupancy. REGISTER LAW:
//    arch-VGPR alloc = 256/min_waves; k_edge's live state fits only w=4
//    (r1 w=8, r3 w=6, r10 w=6 all spilled — WRITE_SIZE tripwire). Resisted
//    VMEM-issue cut (r8: +1.5%), VALU cut (r9: -9us then flat), shuffle cut
//    (r11: ±0). Unexplored: bf16-MFMA phase B (absmax risk at 0.125).
//  * non-edge ~225us: node_down is L2-BW-bound on weight streams (r14:
//    occupancy raise via LDS halving = -20us regression, reverted).
//    Weight amortization via LDS broadcast captured in r6 (+27us).
//    No s_load activation chains (r4). No d_ws cross-iteration caching
//    (r12: harness re-poison + checksum atomic contention).
//  * kernel_launch: ONLY kernel launches (r7 memset rider -> capture fail).
//  * k_edge band on identical bytes: 252-291us (container variance).
// ---------------------------------------------------------------------------
__global__ __launch_bounds__(256, 8) void k_zero_cnt(int* __restrict__ cnt) {
    const int i = blockIdx.x * 256 + threadIdx.x;
    if (i < N_NODES) cnt[i] = 0;
}
__global__ __launch_bounds__(256, 8) void k_hist(const int* __restrict__ rcv,
                                                 int* __restrict__ cnt) {
    const int e = blockIdx.x * 256 + threadIdx.x;
    if (e < N_EDGES) atomicAdd(&cnt[rcv[e]], 1);
}
__global__ __launch_bounds__(1024) void k_scan(const int* __restrict__ cnt,
                                               int* __restrict__ cursor) {
    __shared__ int part[1024];
    const int t = threadIdx.x;
    const int base = t * 20;
    int s = 0;
    #pragma unroll
    for (int j = 0; j < 20; ++j) {
        const int idx = base + j;
        if (idx < N_NODES) s += cnt[idx];
    }
    part[t] = s;
    __syncthreads();
    for (int d = 1; d < 1024; d <<= 1) {
        const int v = (t >= d) ? part[t - d] : 0;
        __syncthreads();
        part[t] += v;
        __syncthreads();
    }
    int run = (t == 0) ? 0 : part[t - 1];
    for (int j = 0; j < 20; ++j) {
        const int idx = base + j;
        if (idx < N_NODES) { cursor[idx] = run; run += cnt[idx]; }
    }
}
__global__ __launch_bounds__(256, 8) void k_scatter(const int* __restrict__ rcv,
                                                    int* __restrict__ cursor,
                                                    int* __restrict__ perm) {
    const int e = blockIdx.x * 256 + threadIdx.x;
    if (e < N_EDGES) {
        const int pos = atomicAdd(&cursor[rcv[e]], 1);
        perm[pos] = e;
    }
}

// ---------------------------------------------------------------------------
// K1 v4: LDS-broadcast amortized + quad-transposed epilogue (r8-r13 measured).
// ---------------------------------------------------------------------------
__global__ __launch_bounds__(256) void k_node_up(
    const float* __restrict__ ns, const float* __restrict__ nv,
    const float* __restrict__ Wus, const float* __restrict__ Wuv,
    float* __restrict__ s_up, float* __restrict__ v_up,
    float* __restrict__ agg_s, float* __restrict__ agg_v)
{
    __shared__ v4f actu[16*64];   // 16KB: [n][i] = {s_i, v_i0, v_i1, v_i2}

    const int tid  = threadIdx.x;
    const int lane = tid & 63;
    const int wq   = __builtin_amdgcn_readfirstlane(tid >> 6);
    const int nb   = blockIdx.x * 16;

    #pragma unroll
    for (int k = 0; k < 4; ++k) {
        const int idx = k*256 + tid;
        const int n = idx >> 6, i = idx & 63;
        const float* nvp = nv + (nb + n)*192 + 3*i;
        actu[idx] = (v4f){ns[(nb + n)*64 + i], nvp[0], nvp[1], nvp[2]};
    }
    __syncthreads();

    float acc[4] = {0.f, 0.f, 0.f, 0.f};
    float a0[4] = {}, a1[4] = {}, a2[4] = {};
    const v4f* aw = actu + wq*4*64;
    for (int i = 0; i < 64; ++i) {
        const float wu = Wus[i*64 + lane];
        const float wv = Wuv[i*64 + lane];
        #pragma unroll
        for (int j = 0; j < 4; ++j) {
            const v4f a = aw[j*64 + i];      // uniform ds_read_b128 broadcast
            acc[j] = fmaf(a.x, wu, acc[j]);
            a0[j]  = fmaf(a.y, wv, a0[j]);
            a1[j]  = fmaf(a.z, wv, a1[j]);
            a2[j]  = fmaf(a.w, wv, a2[j]);
        }
    }
    const int cc = lane & 15, nt = lane >> 4;   // channel = nt*16 + cc
    #pragma unroll
    for (int j = 0; j < 4; ++j) {
        const int n = nb + wq*4 + j;
        s_up[n*64 + cc*4 + nt] = acc[j];             // quad-transposed
        float* vq = v_up + n*192 + cc*12 + nt*3;     // quad-transposed
        vq[0] = a0[j]; vq[1] = a1[j]; vq[2] = a2[j];
        agg_s[n*128 + lane]      = 0.f;
        agg_s[n*128 + 64 + lane] = 0.f;
        #pragma unroll
        for (int k = 0; k < 6; ++k) agg_v[n*384 + k*64 + lane] = 0.f;
    }
}

// ---------------------------------------------------------------------------
// K2 v13 (META-LDS AT w=4, r11/r13 measured-best — byte-identical).
// ---------------------------------------------------------------------------
__global__ __launch_bounds__(256, 4) void k_edge(
    const float* __restrict__ vecs,
    const int*   __restrict__ snd_idx, const int* __restrict__ rcv_idx,
    const int*   __restrict__ perm,
    const float* __restrict__ W0, const float* __restrict__ W1,
    const float* __restrict__ W2,
    const float* __restrict__ s_up, const float* __restrict__ v_up,
    float* __restrict__ agg_s, float* __restrict__ agg_v)
{
    __shared__ float hv[64*68];   // [ch][le], stride 68; holds h1 then h2
    __shared__ v4f   meta[64*2];  // [edge]: {rcvf,sndf,Y0,Y1},{Y2,s1,c1,pref}

    const int tid  = threadIdx.x;
    const int lane = tid & 63;
    const int wq   = __builtin_amdgcn_readfirstlane(tid >> 6);
    const int e0   = blockIdx.x * 64;
    const int c    = lane & 15, q = lane >> 4;
    const float* mb = (const float*)meta;

    // --- edge metadata -> LDS (each wave writes identical values: benign) ---
    {
        const int pe  = perm[e0 + lane];
        const int rcv = rcv_idx[pe];
        const int snd = snd_idx[pe];
        const float vx = vecs[pe*3+0], vy = vecs[pe*3+1], vz = vecs[pe*3+2];
        const float x  = sqrtf(vx*vx + vy*vy + vz*vz);
        const float sx = (x == 0.f) ? 1.f : x;
        const float ys = SQRT3_F / sx;
        float s1, c1;
        __sincosf(PI_F * x, &s1, &c1);
        const float u  = fminf(x, 1.f);
        const float u2 = u*u, u3 = u2*u;
        const float u6 = u3*u3, u7 = u6*u, u8 = u6*u2;
        const float env = (x < 1.f) ? (1.f - 28.f*u6 + 48.f*u7 - 21.f*u8) : 0.f;
        // mask folded: x==0 -> pref=0 -> h1=0 -> h2=swish(0)=0 -> mix==0
        const float pref = (x == 0.f) ? 0.f : (SQRT2_F * env / sx);
        meta[lane*2 + 0] = (v4f){__int_as_float(rcv), __int_as_float(snd),
                                 vx*ys, vy*ys};
        meta[lane*2 + 1] = (v4f){vz*ys, s1, c1, pref};
    }

    // ---- A1: bessel + layer0 -> h1; scalars from own-wave meta entries ----
    float h1o[16];
    #pragma unroll 4
    for (int t = 0; t < 16; ++t) {
        const int le = wq*16 + t;
        const v4f m1 = meta[le*2 + 1];       // uniform addr -> broadcast
        const float pref = m1.w;
        const float twoc = 2.f * m1.z;
        float acc1 = 0.f;
        float sn = m1.y, snm1 = 0.f;
        #pragma unroll
        for (int b = 0; b < 8; ++b) {
            acc1 = fmaf(sn, W0[b*64 + lane], acc1);
            const float snext = fmaf(twoc, sn, -snm1);
            snm1 = sn; sn = snext;
        }
        h1o[t] = swish_f(pref * acc1);
    }
    {   // write own channel-row, own wave's 16 edge-columns: 4x ds_write_b128
        float* dst = hv + lane*68 + wq*16;
        #pragma unroll
        for (int k = 0; k < 4; ++k)
            ((v4f*)dst)[k] = (v4f){h1o[4*k], h1o[4*k+1], h1o[4*k+2], h1o[4*k+3]};
    }
    // no barrier: A2 reads only columns wq*16..+15, written by this wave.

    // ---- A2: h2 = swish(h1 @ W1); own rows/cols, in-place ----
    {
        v2f acc2[8];
        #pragma unroll
        for (int tp = 0; tp < 8; ++tp) acc2[tp] = (v2f){0.f, 0.f};
        const float* hbase = hv + wq*16;
        for (int i = 0; i < 64; ++i) {
            const float w = W1[i*64 + lane];           // coalesced, L1-hot
            const v2f wv = {w, w};
            const v4f* hp4 = (const v4f*)(hbase + i*68);
            #pragma unroll
            for (int k = 0; k < 4; ++k) {
                const v4f h4 = hp4[k];
                const v2f hlo = __builtin_shufflevector(h4, h4, 0, 1);
                const v2f hhi = __builtin_shufflevector(h4, h4, 2, 3);
                acc2[2*k]   = __builtin_elementwise_fma(hlo, wv, acc2[2*k]);
                acc2[2*k+1] = __builtin_elementwise_fma(hhi, wv, acc2[2*k+1]);
            }
        }
        float* dst = hv + lane*68 + wq*16;
        #pragma unroll
        for (int k = 0; k < 4; ++k)
            ((v4f*)dst)[k] = (v4f){swish_f(acc2[2*k][0]),   swish_f(acc2[2*k][1]),
                                   swish_f(acc2[2*k+1][0]), swish_f(acc2[2*k+1][1])};
    }
    __syncthreads();

    // ---- B: mixp[t/2][ntl] pairs; lane (c,q) of wave wq accumulates
    //      mix[64wq + ntl*16 + c][le = q*16 + t] for t=0..15.
    v2f mixp[8][4];
    #pragma unroll
    for (int tp = 0; tp < 8; ++tp)
        #pragma unroll
        for (int j = 0; j < 4; ++j) mixp[tp][j] = (v2f){0.f, 0.f};
    {
        const float* W2c = W2 + 64*wq + c;
        const float* hq  = hv + q*16;
        for (int i = 0; i < 64; ++i) {
            const float w0 = W2c[i*256 +  0];
            const float w1 = W2c[i*256 + 16];
            const float w2 = W2c[i*256 + 32];
            const float w3 = W2c[i*256 + 48];
            const v2f w0v = {w0,w0}, w1v = {w1,w1}, w2v = {w2,w2}, w3v = {w3,w3};
            const v4f* hp4 = (const v4f*)(hq + i*68);
            #pragma unroll
            for (int k = 0; k < 4; ++k) {
                const v4f h4 = hp4[k];
                const v2f hlo = __builtin_shufflevector(h4, h4, 0, 1);
                const v2f hhi = __builtin_shufflevector(h4, h4, 2, 3);
                mixp[2*k][0]   = __builtin_elementwise_fma(hlo, w0v, mixp[2*k][0]);
                mixp[2*k][1]   = __builtin_elementwise_fma(hlo, w1v, mixp[2*k][1]);
                mixp[2*k][2]   = __builtin_elementwise_fma(hlo, w2v, mixp[2*k][2]);
                mixp[2*k][3]   = __builtin_elementwise_fma(hlo, w3v, mixp[2*k][3]);
                mixp[2*k+1][0] = __builtin_elementwise_fma(hhi, w0v, mixp[2*k+1][0]);
                mixp[2*k+1][1] = __builtin_elementwise_fma(hhi, w1v, mixp[2*k+1][1]);
                mixp[2*k+1][2] = __builtin_elementwise_fma(hhi, w2v, mixp[2*k+1][2]);
                mixp[2*k+1][3] = __builtin_elementwise_fma(hhi, w3v, mixp[2*k+1][3]);
            }
        }
    }
    #define MIXR(t,j) (mixp[(t)>>1][j][(t)&1])

    // ---- C: per-q-group segmented scatter-add; meta from LDS broadcast ----
    int cur = -1;
    if (wq == 0) {            // agg_s[:, ntl*16+c] += msv * mix0
        float ra0=0.f, ra1=0.f, ra2=0.f, ra3=0.f;
        #pragma unroll
        for (int t = 0; t < 16; ++t) {
            const int el = (lane & 48) + t;
            const v2f rs = *(const v2f*)(mb + el*8);   // {rcvf, sndf}
            const int rcv = __float_as_int(rs.x);
            const int snd = __float_as_int(rs.y);
            if (rcv != cur) {
                if (cur >= 0) {
                    float* p = agg_s + cur*128 + c;
                    unsafeAtomicAdd(p,      ra0);
                    unsafeAtomicAdd(p + 16, ra1);
                    unsafeAtomicAdd(p + 32, ra2);
                    unsafeAtomicAdd(p + 48, ra3);
                }
                ra0 = ra1 = ra2 = ra3 = 0.f; cur = rcv;
            }
            const v4f sv = *(const v4f*)(s_up + snd*64 + c*4);
            ra0 = fmaf(sv.x, MIXR(t,0), ra0);
            ra1 = fmaf(sv.y, MIXR(t,1), ra1);
            ra2 = fmaf(sv.z, MIXR(t,2), ra2);
            ra3 = fmaf(sv.w, MIXR(t,3), ra3);
        }
        float* p = agg_s + cur*128 + c;
        unsafeAtomicAdd(p,      ra0);
        unsafeAtomicAdd(p + 16, ra1);
        unsafeAtomicAdd(p + 32, ra2);
        unsafeAtomicAdd(p + 48, ra3);
    } else if (wq == 1) {     // agg_s[:, 64+ntl*16+c] += (mv.Y)/sqrt3 * mix1
        float ra0=0.f, ra1=0.f, ra2=0.f, ra3=0.f;
        #pragma unroll
        for (int t = 0; t < 16; ++t) {
            const int el = (lane & 48) + t;
            const v4f m0 = meta[el*2];                 // {rcvf,sndf,Y0,Y1}
            const float Y2 = mb[el*8 + 4];
            const int rcv = __float_as_int(m0.x);
            const int snd = __float_as_int(m0.y);
            const float Y0 = m0.z, Y1 = m0.w;
            if (rcv != cur) {
                if (cur >= 0) {
                    float* p = agg_s + cur*128 + 64 + c;
                    unsafeAtomicAdd(p,      ra0);
                    unsafeAtomicAdd(p + 16, ra1);
                    unsafeAtomicAdd(p + 32, ra2);
                    unsafeAtomicAdd(p + 48, ra3);
                }
                ra0 = ra1 = ra2 = ra3 = 0.f; cur = rcv;
            }
            const float* vb = v_up + snd*192 + c*12;
            const v4f f0 = *(const v4f*)(vb);
            const v4f f1 = *(const v4f*)(vb + 4);
            const v4f f2 = *(const v4f*)(vb + 8);
            const float t00 = (f0.x*Y0 + f0.y*Y1 + f0.z*Y2) * INV_SQRT3_F;
            const float t01 = (f0.w*Y0 + f1.x*Y1 + f1.y*Y2) * INV_SQRT3_F;
            const float t02 = (f1.z*Y0 + f1.w*Y1 + f2.x*Y2) * INV_SQRT3_F;
            const float t03 = (f2.y*Y0 + f2.z*Y1 + f2.w*Y2) * INV_SQRT3_F;
            ra0 = fmaf(t00, MIXR(t,0), ra0);
            ra1 = fmaf(t01, MIXR(t,1), ra1);
            ra2 = fmaf(t02, MIXR(t,2), ra2);
            ra3 = fmaf(t03, MIXR(t,3), ra3);
        }
        float* p = agg_s + cur*128 + 64 + c;
        unsafeAtomicAdd(p,      ra0);
        unsafeAtomicAdd(p + 16, ra1);
        unsafeAtomicAdd(p + 32, ra2);
        unsafeAtomicAdd(p + 48, ra3);
    } else if (wq == 2) {     // agg_v[:, ntl*16+c, m] += mv_m * mix2
        float rv[4][3];
        #pragma unroll
        for (int i = 0; i < 4; ++i) { rv[i][0]=0.f; rv[i][1]=0.f; rv[i][2]=0.f; }
        #pragma unroll
        for (int t = 0; t < 16; ++t) {
            const int el = (lane & 48) + t;
            const v2f rs = *(const v2f*)(mb + el*8);   // {rcvf, sndf}
            const int rcv = __float_as_int(rs.x);
            const int snd = __float_as_int(rs.y);
            if (rcv != cur) {
                if (cur >= 0) {
                    float* p = agg_v + cur*384 + c*3;
                    #pragma unroll
                    for (int ntl = 0; ntl < 4; ++ntl)
                        #pragma unroll
                        for (int m = 0; m < 3; ++m)
                            unsafeAtomicAdd(p + ntl*48 + m, rv[ntl][m]);
                }
                #pragma unroll
                for (int i = 0; i < 4; ++i) { rv[i][0]=0.f; rv[i][1]=0.f; rv[i][2]=0.f; }
                cur = rcv;
            }
            const float* vb = v_up + snd*192 + c*12;
            const v4f f0 = *(const v4f*)(vb);
            const v4f f1 = *(const v4f*)(vb + 4);
            const v4f f2 = *(const v4f*)(vb + 8);
            const float mx0 = MIXR(t,0);
            const float mx1 = MIXR(t,1);
            const float mx2 = MIXR(t,2);
            const float mx3 = MIXR(t,3);
            rv[0][0] = fmaf(f0.x, mx0, rv[0][0]);
            rv[0][1] = fmaf(f0.y, mx0, rv[0][1]);
            rv[0][2] = fmaf(f0.z, mx0, rv[0][2]);
            rv[1][0] = fmaf(f0.w, mx1, rv[1][0]);
            rv[1][1] = fmaf(f1.x, mx1, rv[1][1]);
            rv[1][2] = fmaf(f1.y, mx1, rv[1][2]);
            rv[2][0] = fmaf(f1.z, mx2, rv[2][0]);
            rv[2][1] = fmaf(f1.w, mx2, rv[2][1]);
            rv[2][2] = fmaf(f2.x, mx2, rv[2][2]);
            rv[3][0] = fmaf(f2.y, mx3, rv[3][0]);
            rv[3][1] = fmaf(f2.z, mx3, rv[3][1]);
            rv[3][2] = fmaf(f2.w, mx3, rv[3][2]);
        }
        float* p = agg_v + cur*384 + c*3;
        #pragma unroll
        for (int ntl = 0; ntl < 4; ++ntl)
            #pragma unroll
            for (int m = 0; m < 3; ++m)
                unsafeAtomicAdd(p + ntl*48 + m, rv[ntl][m]);
    } else {                  // agg_v[:, 64+ntl*16+c, m] += msv * Y_m * mix3
        float rv[4][3];
        #pragma unroll
        for (int i = 0; i < 4; ++i) { rv[i][0]=0.f; rv[i][1]=0.f; rv[i][2]=0.f; }
        #pragma unroll
        for (int t = 0; t < 16; ++t) {
            const int el = (lane & 48) + t;
            const v4f m0 = meta[el*2];                 // {rcvf,sndf,Y0,Y1}
            const float Y2 = mb[el*8 + 4];
            const int rcv = __float_as_int(m0.x);
            const int snd = __float_as_int(m0.y);
            const float Y0 = m0.z, Y1 = m0.w;
            if (rcv != cur) {
                if (cur >= 0) {
                    float* p = agg_v + cur*384 + 192 + c*3;
                    #pragma unroll
                    for (int ntl = 0; ntl < 4; ++ntl)
                        #pragma unroll
                        for (int m = 0; m < 3; ++m)
                            unsafeAtomicAdd(p + ntl*48 + m, rv[ntl][m]);
                }
                #pragma unroll
                for (int i = 0; i < 4; ++i) { rv[i][0]=0.f; rv[i][1]=0.f; rv[i][2]=0.f; }
                cur = rcv;
            }
            const v4f sv = *(const v4f*)(s_up + snd*64 + c*4);
            const float mm0 = sv.x * MIXR(t,0);
            const float mm1 = sv.y * MIXR(t,1);
            const float mm2 = sv.z * MIXR(t,2);
            const float mm3 = sv.w * MIXR(t,3);
            rv[0][0] = fmaf(mm0, Y0, rv[0][0]);
            rv[0][1] = fmaf(mm0, Y1, rv[0][1]);
            rv[0][2] = fmaf(mm0, Y2, rv[0][2]);
            rv[1][0] = fmaf(mm1, Y0, rv[1][0]);
            rv[1][1] = fmaf(mm1, Y1, rv[1][1]);
            rv[1][2] = fmaf(mm1, Y2, rv[1][2]);
            rv[2][0] = fmaf(mm2, Y0, rv[2][0]);
            rv[2][1] = fmaf(mm2, Y1, rv[2][1]);
            rv[2][2] = fmaf(mm2, Y2, rv[2][2]);
            rv[3][0] = fmaf(mm3, Y0, rv[3][0]);
            rv[3][1] = fmaf(mm3, Y1, rv[3][1]);
            rv[3][2] = fmaf(mm3, Y2, rv[3][2]);
        }
        float* p = agg_v + cur*384 + 192 + c*3;
        #pragma unroll
        for (int ntl = 0; ntl < 4; ++ntl)
            #pragma unroll
            for (int m = 0; m < 3; ++m)
                unsafeAtomicAdd(p + ntl*48 + m, rv[ntl][m]);
    }
    #undef MIXR
}

// ---------------------------------------------------------------------------
// K3 v3 (LDS-BROADCAST AMORTIZED, r6/r13 measured-best form; r14's half-
// staged variant regressed -20us and was reverted).
// ---------------------------------------------------------------------------
__global__ __launch_bounds__(256) void k_node_down(
    const float* __restrict__ ns, const float* __restrict__ nv,
    const int*   __restrict__ spec_idx,
    const float* __restrict__ Wds, const float* __restrict__ Wdv,
    const float* __restrict__ Wsks, const float* __restrict__ Wskv,
    const float* __restrict__ agg_s, const float* __restrict__ agg_v,
    float* __restrict__ out)
{
    __shared__ v4f act[16*128];  // 32KB: [n][i] = {a, av0, av1, av2} * INV_AVG
    __shared__ v4f skp[16*64];   // 16KB: [n][i] = {s, v0, v1, v2}

    const int tid  = threadIdx.x;
    const int lane = tid & 63;
    const int wq   = __builtin_amdgcn_readfirstlane(tid >> 6);
    const int nb   = blockIdx.x * 16;

    #pragma unroll
    for (int k = 0; k < 8; ++k) {
        const int idx = k*256 + tid;
        const int n = idx >> 7, i = idx & 127;
        const float a = agg_s[(nb + n)*128 + i] * INV_AVG;
        const float* av = agg_v + (nb + n)*384 + 3*i;
        act[idx] = (v4f){a, av[0]*INV_AVG, av[1]*INV_AVG, av[2]*INV_AVG};
    }
    #pragma unroll
    for (int k = 0; k < 4; ++k) {
        const int idx = k*256 + tid;
        const int n = idx >> 6, i = idx & 63;
        const float* nvp = nv + (nb + n)*192 + 3*i;
        skp[idx] = (v4f){ns[(nb + n)*64 + i], nvp[0], nvp[1], nvp[2]};
    }
    __syncthreads();

    float s0[4] = {}, s1[4] = {}, v0[4] = {}, v1[4] = {}, v2[4] = {};

    const v4f* aw = act + wq*4*128;
    for (int i = 0; i < 128; ++i) {
        const float wd0 = Wds[i*128 + lane];
        const float wd1 = Wds[i*128 + 64 + lane];
        const float wdv = Wdv[i*64 + lane];
        #pragma unroll
        for (int j = 0; j < 4; ++j) {
            const v4f a = aw[j*128 + i];     // uniform ds_read_b128 broadcast
            s0[j] = fmaf(a.x, wd0, s0[j]);
            s1[j] = fmaf(a.x, wd1, s1[j]);
            v0[j] = fmaf(a.y, wdv, v0[j]);
            v1[j] = fmaf(a.z, wdv, v1[j]);
            v2[j] = fmaf(a.w, wdv, v2[j]);
        }
    }

    const int n0 = nb + wq*4;
    const float* Ws_j[4]; const float* Wv_j[4];
    #pragma unroll
    for (int j = 0; j < 4; ++j) {
        const int spec = __builtin_amdgcn_readfirstlane(spec_idx[n0 + j]);
        Ws_j[j] = Wsks + spec*8192;   // (64,128)
        Wv_j[j] = Wskv + spec*4096;   // (64,64)
    }
    const v4f* sw = skp + wq*4*64;
    for (int i = 0; i < 64; ++i) {
        #pragma unroll
        for (int j = 0; j < 4; ++j) {
            const v4f a = sw[j*64 + i];      // uniform ds_read_b128 broadcast
            s0[j] = fmaf(a.x, Ws_j[j][i*128 + lane], s0[j]);
            s1[j] = fmaf(a.x, Ws_j[j][i*128 + 64 + lane], s1[j]);
            const float wv = Wv_j[j][i*64 + lane];
            v0[j] = fmaf(a.y, wv, v0[j]);
            v1[j] = fmaf(a.z, wv, v1[j]);
            v2[j] = fmaf(a.w, wv, v2[j]);
        }
    }

    #pragma unroll
    for (int j = 0; j < 4; ++j) {
        const int n = n0 + j;
        const float scal = swish_f(s0[j]);
        const float gate = swish_f(s1[j]);
        out[n*256 + lane]            = scal;
        out[n*256 + 64 + lane*3 + 0] = v0[j] * gate;
        out[n*256 + 64 + lane*3 + 1] = v1[j] * gate;
        out[n*256 + 64 + lane*3 + 2] = v2[j] * gate;
    }
}

// ---------------------------------------------------------------------------
extern "C" void kernel_launch(void* const* d_in, const int* in_sizes, int n_in,
                              void* d_out, int out_size, void* d_ws, size_t ws_size,
                              hipStream_t stream)
{
    (void)in_sizes; (void)n_in; (void)out_size; (void)ws_size;

    const float* vectors      = (const float*)d_in[0];
    const float* node_scalars = (const float*)d_in[1];
    const float* node_vectors = (const float*)d_in[2];
    const int*   node_specie  = (const int*)d_in[3];
    const int*   senders      = (const int*)d_in[4];
    const int*   receivers    = (const int*)d_in[5];
    const float* W_skip_s     = (const float*)d_in[6];
    const float* W_skip_v     = (const float*)d_in[7];
    const float* W_up_s       = (const float*)d_in[8];
    const float* W_up_v       = (const float*)d_in[9];
    const float* W_mlp0       = (const float*)d_in[10];
    const float* W_mlp1       = (const float*)d_in[11];
    const float* W_mlp2       = (const float*)d_in[12];
    const float* W_down_s     = (const float*)d_in[13];
    const float* W_down_v     = (const float*)d_in[14];
    float* out = (float*)d_out;

    // workspace layout: 15,360,000 f32 + perm 320k ints.
    float* ws    = (float*)d_ws;
    float* s_up  = ws;                        // N*64   = 1,280,000 f32 (quad-T)
    float* v_up  = s_up + 1280000;            // N*192  = 3,840,000    (quad-T)
    float* agg_s = v_up + 3840000;            // N*128  = 2,560,000
    float* agg_v = agg_s + 2560000;           // N*384  = 7,680,000
    int*   perm  = (int*)(agg_v + 7680000);   // E ints = 320,000
    int*   cnt    = (int*)agg_s;              // aliased scratch (dead before node_up)
    int*   cursor = cnt + 20000;

    // edge counting sort by receiver (kernels only; no runtime memops)
    hipLaunchKernelGGL(k_zero_cnt, dim3(79),   dim3(256),  0, stream, cnt);
    hipLaunchKernelGGL(k_hist,     dim3(1250), dim3(256),  0, stream, receivers, cnt);
    hipLaunchKernelGGL(k_scan,     dim3(1),    dim3(1024), 0, stream, cnt, cursor);
    hipLaunchKernelGGL(k_scatter,  dim3(1250), dim3(256),  0, stream, receivers, cursor, perm);

    hipLaunchKernelGGL(k_node_up, dim3(1250), dim3(256), 0, stream,
        node_scalars, node_vectors, W_up_s, W_up_v, s_up, v_up, agg_s, agg_v);
    hipLaunchKernelGGL(k_edge, dim3(5000), dim3(256), 0, stream,
        vectors, senders, receivers, perm, W_mlp0, W_mlp1, W_mlp2,
        s_up, v_up, agg_s, agg_v);
    hipLaunchKernelGGL(k_node_down, dim3(1250), dim3(256), 0, stream,
        node_scalars, node_vectors, node_specie, W_down_s, W_down_v,
        W_skip_s, W_skip_v, agg_s, agg_v, out);
}